// Round 11
// baseline (445.610 us; speedup 1.0000x reference)
//
#include <hip/hip_runtime.h>

// TinyLSTM: I=128, H=64, C=10, B=256, T=1024
// R15 = R9/R14 structure (306/311us rocprof -- best; all counters <10% =
// serial-latency wall) + two chain-latency-only shaves (the law from
// R8-R13: added ISSUE work costs ~1:1; these add none):
//  1) g-gate split-K: a2=mfma(A0,hb0,seed); u2=mfma(A1,hb1,0) issue
//     back-to-back (no C-dep stall) -> g=a2[cr]+u2[cr]. Saves ~1 MFMA
//     dep-latency (~40cyc) at the act-chain head for +1 extract/add (~20).
//     (seed+S0)+S1 in both forms -> expected bit-identical.
//  2) seed load_xa hoisted BEFORE the MFMA block: lgkm retires in-order, so
//     the 4 seed reads retire under MFMA issue instead of adding a tail to
//     the pre-barrier lgkmcnt(0) drain.
// Producers, slots, sync ledger: byte-identical to R9. History:
//  R8 1015 cyc/step (bulk on path) | R9 719 BEST | R10 1153 (xproj folded
//  into consumer: no co-issue at 1 wave/SIMD) | R11 1195 / R12 1316 (global
//  rings: "memory"-clobber barrier drains vmcnt every step) | R13 844
//  (clobberless barrier + split burst: added LDS-latency exposure) |
//  R14 727 (g-first order: null).
// (Rounds 6/8/10 were GPUAcquisitionTimeouts; R15 resubmitted unchanged.)

#define NI 128
#define NH 64
#define NB 256
#define NT 1024
#define NC 10

#define TT 4
#define NTILE (NT / TT)

#define LOG2E    1.44269504f
#define TWOLOG2E 2.88539008f

typedef __fp16 half2v __attribute__((ext_vector_type(2)));
typedef __fp16 f16x8  __attribute__((ext_vector_type(8)));
typedef float  f32x4  __attribute__((ext_vector_type(4)));

#define HP  80           // H row stride (halves): 160 B, max 2-way banks
#define XPB 268          // xproj batch stride (floats)
#define XPT (4 * XPB)    // xproj timestep stride (floats)

#define MF(acc, a, b) \
    acc = __builtin_amdgcn_mfma_f32_16x16x32_f16(a, b, acc, 0, 0, 0)

__device__ __forceinline__ void block_sync_lds() {
    asm volatile("s_waitcnt lgkmcnt(0)\n\ts_barrier" ::: "memory");
}
__device__ __forceinline__ void wave_drain_vm() {
    asm volatile("s_waitcnt vmcnt(0)" ::: "memory");
}
__device__ __forceinline__ float fast_exp2(float x) {
#if __has_builtin(__builtin_amdgcn_exp2f)
    return __builtin_amdgcn_exp2f(x);
#else
    return __exp2f(x);
#endif
}
__device__ __forceinline__ float fast_rcp(float x) {
    return __builtin_amdgcn_rcpf(x);
}
__device__ __forceinline__ f16x8 pack8(float4 a, float4 b, float s) {
    half2v p0 = __builtin_amdgcn_cvt_pkrtz(a.x * s, a.y * s);
    half2v p1 = __builtin_amdgcn_cvt_pkrtz(a.z * s, a.w * s);
    half2v p2 = __builtin_amdgcn_cvt_pkrtz(b.x * s, b.y * s);
    half2v p3 = __builtin_amdgcn_cvt_pkrtz(b.z * s, b.w * s);
    f16x8 r;
    r[0]=p0[0]; r[1]=p0[1]; r[2]=p1[0]; r[3]=p1[1];
    r[4]=p2[0]; r[5]=p2[1]; r[6]=p3[0]; r[7]=p3[1];
    return r;
}
__device__ __forceinline__ f16x8 pack8n(float4 a, float4 b) {
    half2v p0 = __builtin_amdgcn_cvt_pkrtz(a.x, a.y);
    half2v p1 = __builtin_amdgcn_cvt_pkrtz(a.z, a.w);
    half2v p2 = __builtin_amdgcn_cvt_pkrtz(b.x, b.y);
    half2v p3 = __builtin_amdgcn_cvt_pkrtz(b.z, b.w);
    f16x8 r;
    r[0]=p0[0]; r[1]=p0[1]; r[2]=p1[0]; r[3]=p1[1];
    r[4]=p2[0]; r[5]=p2[1]; r[6]=p3[0]; r[7]=p3[1];
    return r;
}
__device__ __forceinline__ void gload_lds16(const void* g, void* l) {
    __builtin_amdgcn_global_load_lds(
        (const __attribute__((address_space(1))) unsigned int*)g,
        (__attribute__((address_space(3))) unsigned int*)l, 16, 0, 0);
}

__global__ __launch_bounds__(512, 2)
void lstm_one(const float* __restrict__ x,
              const float* __restrict__ W_ih,
              const float* __restrict__ W_hh,
              const float* __restrict__ b_ih,
              const float* __restrict__ b_hh,
              const float* __restrict__ W_cls,
              const float* __restrict__ b_cls,
              float* __restrict__ out) {
    const int tid  = threadIdx.x;
    const int w4   = tid >> 6;          // 0..7
    const bool cons = (w4 < 4);         // waves 0-3: recurrence consumers
    const int w    = w4 & 3;            // role-local wave id
    const int lane = tid & 63;
    const int col  = lane & 15;         // MFMA n-column
    const int quad = lane >> 4;
    const int bb   = blockIdx.x;        // batches [4bb, 4bb+4)
    const int bcol = col & 3;           // batch within group
    const int cr   = col >> 2;

    __shared__ __align__(16) float  XS[2][4][TT * NI];  // raw x, dbl-buf 16K
    __shared__ __align__(16) float  P[2][TT * XPT];     // xproj f32, dbl 34.3K
    __shared__ __align__(16) __fp16 H2[2][4][HP];       // h f16, dbl-buf 1.3K

    if (!cons) {
        // ================= PRODUCER (waves 4-7) =================
        // stage batch (4bb+w), tile -> XS[tile&1][w]. LDS dest linear; src
        // addr ^xo, xo=((row^(row>>1))&7)<<4, row=(w*2048+lin)>>9.
        // Involutive, within-128B-line: coalescing unchanged, 2-way LDS.
        auto stage_x = [&](int tile) {
            const char* xsrc = (const char*)(x + ((size_t)(4 * bb + w) * NT
                                                  + (size_t)tile * TT) * NI);
            #pragma unroll
            for (int j = 0; j < 2; ++j) {
                const unsigned lin = j * 1024u + (unsigned)lane * 16u;
                const unsigned row = ((unsigned)w * 2048u + lin) >> 9;
                const unsigned xo  = ((row ^ (row >> 1)) & 7u) << 4;
                gload_lds16(xsrc + (lin ^ xo),
                            (char*)&XS[tile & 1][w][0] + j * 1024);
            }
        };
        stage_x(0);
        stage_x(1);

        // W_ih A-frags + prescaled bias (producer only)
        f16x8 afrX[4][4];
        f32x4 biasf[4];
        #pragma unroll
        for (int i = 0; i < 4; ++i) {
            const int grow = 64 * i + 16 * w + col;
            const float s = (i == 2) ? TWOLOG2E : LOG2E;
            const float* Wx = W_ih + (size_t)grow * NI;
            #pragma unroll
            for (int ks = 0; ks < 4; ++ks) {
                float4 a4 = *(const float4*)(Wx + ks * 32 + quad * 8);
                float4 b4 = *(const float4*)(Wx + ks * 32 + quad * 8 + 4);
                afrX[i][ks] = pack8(a4, b4, s);
            }
            #pragma unroll
            for (int r = 0; r < 4; ++r) {
                const int u = 64 * i + 16 * w + 4 * quad + r;
                biasf[i][r] = (b_ih[u] + b_hh[u]) * s;
            }
        }

        // produce xproj for tile tp: reads XS[tp&1] (all batches -> needs all
        // producers' stages visible: each drained own vmcnt + barrier before)
        auto produce = [&](int tp) {
            const char* XSb = (const char*)&XS[tp & 1][0][0];
            const int tl = cr;                         // timestep 0..3
            const unsigned row = (unsigned)(bcol * 4 + tl);
            const unsigned xo  = ((row ^ (row >> 1)) & 7u) << 4;
            const unsigned rb  = row * 512u + (unsigned)quad * 32u;
            f16x8 xb[4];
            #pragma unroll
            for (int ks = 0; ks < 4; ++ks) {
                const unsigned l0 = rb + ks * 128u;
                float4 p0 = *(const float4*)(XSb + (l0 ^ xo));
                float4 p1 = *(const float4*)(XSb + ((l0 + 16u) ^ xo));
                xb[ks] = pack8n(p0, p1);
            }
            f32x4 c0 = biasf[0], c1 = biasf[1], c2 = biasf[2], c3 = biasf[3];
            #pragma unroll
            for (int ks = 0; ks < 4; ++ks) {
                MF(c0, afrX[0][ks], xb[ks]);
                MF(c1, afrX[1][ks], xb[ks]);
                MF(c2, afrX[2][ks], xb[ks]);
                MF(c3, afrX[3][ks], xb[ks]);
            }
            float* wp = &P[tp & 1][0] + tl * XPT + bcol * XPB
                        + 16 * w + 4 * quad;
            *(f32x4*)(wp)       = c0;
            *(f32x4*)(wp + 64)  = c1;
            *(f32x4*)(wp + 128) = c2;
            *(f32x4*)(wp + 192) = c3;
        };

        wave_drain_vm();        // x_0, x_1 landed (own)
        block_sync_lds();       // [A] all producers' stages visible
        produce(0);             // P[0] <- xproj tile 0
        block_sync_lds();       // [B] P[0] visible to consumers

        for (int k = 0; k < NTILE; ++k) {
            // slot tt=0: next tile's xproj (reads XS[(k+1)&1], writes
            // P[(k+1)&1]; consumers' last read of that P-buffer was at
            // (k-1,tt=2), >=2 barriers ago)
            if (k + 1 < NTILE) produce(k + 1);
            block_sync_lds();
            // slot tt=1: stage x_{k+2} -> XS[k&1] (last ds_reads of that
            // buffer drained at (k-1,tt=0)'s barrier)
            if (k + 2 < NTILE) stage_x(k + 2);
            block_sync_lds();
            // slot tt=2: idle
            block_sync_lds();
            // slot tt=3: drain own staging loads; the following barrier
            // publishes cross-producer completion before tile k+1 reads
            wave_drain_vm();
            block_sync_lds();
        }
        return;   // no epilogue work; barrier counts matched with consumers
    }

    // ================= CONSUMER (waves 0-3) =================
    __builtin_amdgcn_s_setprio(1);      // recurrence chain is the wall time

    // W_hh A-frags (consumer only; no afrX, no bias -- seed comes from P)
    f16x8 afrH[4][2];
    #pragma unroll
    for (int i = 0; i < 4; ++i) {
        const int grow = 64 * i + 16 * w + col;
        const float s = (i == 2) ? TWOLOG2E : LOG2E;
        const float* Wh = W_hh + (size_t)grow * NH;
        #pragma unroll
        for (int ks = 0; ks < 2; ++ks) {
            float4 a4 = *(const float4*)(Wh + ks * 32 + quad * 8);
            float4 b4 = *(const float4*)(Wh + ks * 32 + quad * 8 + 4);
            afrH[i][ks] = pack8(a4, b4, s);
        }
    }
    for (int z = tid; z < 2 * 4 * HP / 2; z += 256)
        ((unsigned*)H2)[z] = 0u;        // zero both H bufs

    block_sync_lds();       // [A] (match producer)
    block_sync_lds();       // [B] P[0] ready

    float c = 0.f;
    const f32x4 zacc = {0.f, 0.f, 0.f, 0.f};
    f32x4 xa0, xa1, xa2, xa3;           // xproj seed, prefetched (static regs)
    auto load_xa = [&](const float* Pb, int tt) {
        const float* rp = Pb + tt * XPT + bcol * XPB + 16 * w + 4 * quad;
        xa0 = *(const f32x4*)(rp);
        xa1 = *(const f32x4*)(rp + 64);
        xa2 = *(const f32x4*)(rp + 128);
        xa3 = *(const f32x4*)(rp + 192);
    };
    load_xa(&P[0][0], 0);

    for (int k = 0; k < NTILE; ++k) {
        #pragma unroll
        for (int tt = 0; tt < TT; ++tt) {
            const int cur = tt & 1;     // s=4k+tt -> parity = tt&1
            const __fp16* Hc = &H2[cur][bcol][quad * 8];
            f16x8 hb0 = *(const f16x8*)(Hc);
            f16x8 hb1 = *(const f16x8*)(Hc + 32);
            f32x4 a0 = xa0, a1 = xa1, a2 = xa2, a3 = xa3;
            f32x4 u2 = zacc;
            // seed prefetch for next step, issued EARLY: lgkm retires
            // in-order under the MFMA issue window, shrinking the
            // pre-barrier lgkmcnt(0) drain tail. Reads this lane's current
            // xa* first (already copied into a0..a3 above).
            if (tt < TT - 1)           load_xa(&P[k & 1][0], tt + 1);
            else if (k + 1 < NTILE)    load_xa(&P[(k + 1) & 1][0], 0);
            // g-gate split-K: both MFMAs independent (no C-dep stall), then
            // g = a2[cr]+u2[cr] -- (seed+S0)+S1, same sum order as chained.
            MF(a2, afrH[2][0], hb0);
            MF(u2, afrH[2][1], hb1);
            MF(a0, afrH[0][0], hb0);
            MF(a1, afrH[1][0], hb0);
            MF(a0, afrH[0][1], hb1);
            MF(a1, afrH[1][1], hb1);
            MF(a3, afrH[3][0], hb0);
            MF(a3, afrH[3][1], hb1);
            // activation: one unit (u=16w+4quad+cr, batch bcol); paired rcps
            float gg = a2[cr] + u2[cr];
            float Eg = fast_exp2(fminf(gg, 60.f));
            float Ei = fast_exp2(-a0[cr]);
            float Ef = fast_exp2(-a1[cr]);
            float Eo = fast_exp2(-a3[cr]);
            float ig = (Eg - 1.f) * fast_rcp((1.f + Ei) * (1.f + Eg));
            float fv = fast_rcp(1.f + Ef);
            c = fmaf(fv, c, ig);
            float Ec = fast_exp2(fminf(TWOLOG2E * c, 60.f));
            float h  = (Ec - 1.f) * fast_rcp((1.f + Eo) * (1.f + Ec));
            H2[cur ^ 1][bcol][16 * w + 4 * quad + cr] = (__fp16)h;
            block_sync_lds();
        }
    }
    // final h in H2[0] (s=1023: cur=1, writes buf 0); last barrier done.

    if (tid < 4 * NC) {
        const int bl = tid / NC, cl = tid % NC;
        float acc = b_cls[cl];
        const float* wc = W_cls + cl * NH;
        #pragma unroll 8
        for (int kk = 0; kk < NH; ++kk)
            acc = fmaf(wc[kk], (float)H2[0][bl][kk], acc);
        out[(4 * bb + bl) * NC + cl] = acc;
    }
}

extern "C" void kernel_launch(void* const* d_in, const int* in_sizes, int n_in,
                              void* d_out, int out_size, void* d_ws, size_t ws_size,
                              hipStream_t stream) {
    const float* x     = (const float*)d_in[0];
    const float* W_ih  = (const float*)d_in[1];
    const float* W_hh  = (const float*)d_in[2];
    const float* b_ih  = (const float*)d_in[3];
    const float* b_hh  = (const float*)d_in[4];
    const float* W_cls = (const float*)d_in[5];
    const float* b_cls = (const float*)d_in[6];
    float* out = (float*)d_out;

    lstm_one<<<NB / 4, 512, 0, stream>>>(x, W_ih, W_hh, b_ih, b_hh,
                                         W_cls, b_cls, out);
}